// Round 11
// baseline (798.167 us; speedup 1.0000x reference)
//
#include <hip/hip_runtime.h>
#include <hip/hip_fp16.h>

#define NN 50000
#define NE 150000
#define HD 512
#define HIDN 64
#define BN_EPS 1e-5f
#define SLOPE 0.01f
#define NPART 196   // ceil(NN/256)

typedef _Float16 half8 __attribute__((ext_vector_type(8)));
typedef float floatx4 __attribute__((ext_vector_type(4)));

__device__ __forceinline__ float leaky(float v){ return v > 0.f ? v : SLOPE*v; }
__device__ __forceinline__ float h2fu(unsigned short u){ return __half2float(__ushort_as_half(u)); }
__device__ __forceinline__ unsigned short f2hu(float f){ return __half_as_ushort(__float2half(f)); }
__device__ __forceinline__ unsigned packh2(float a, float b){
  return (unsigned)f2hu(a) | ((unsigned)f2hu(b) << 16);
}

// async global->LDS, 16B per lane. LDS dest must be the WAVE-UNIFORM base;
// HW writes each lane at base + lane*16. Global src is per-lane.
__device__ __forceinline__ void gload16(const _Float16* g, _Float16* l){
  __builtin_amdgcn_global_load_lds(
      (const __attribute__((address_space(1))) void*)g,
      (__attribute__((address_space(3))) void*)l, 16, 0, 0);
}

// ---------------- setup: invs (via inline binary-search counts) + mask0 + deg-zero ----------------
__global__ void k_invs_mask0(const int* __restrict__ batch, const float* __restrict__ x,
                             float* __restrict__ invs, int* __restrict__ m0, int* __restrict__ deg){
  int i = blockIdx.x*blockDim.x + threadIdx.x;
  if (i < NN){
    int g = batch[i];
    int lo = 0, hi = NN;
    while (lo < hi){ int mid = (lo+hi)>>1; if (batch[mid] <  g) lo = mid+1; else hi = mid; }
    int start = lo;
    lo = 0; hi = NN;
    while (lo < hi){ int mid = (lo+hi)>>1; if (batch[mid] <= g) lo = mid+1; else hi = mid; }
    invs[i] = rsqrtf((float)(lo - start));
    m0[i] = (fabsf(x[i]) > 0.f) ? 1 : 0;
    deg[i] = 0;
  }
}
__global__ void k_mask_gather(const int* __restrict__ mi, int* __restrict__ mo,
                              const int* __restrict__ off, const int* __restrict__ deg,
                              const int* __restrict__ srcs){
  int i = blockIdx.x*blockDim.x + threadIdx.x;
  if (i < NN){
    int v = mi[i];
    int o = off[i], d = deg[i];
    for (int j = 0; j < d; j++) v |= mi[srcs[o+j]];
    mo[i] = v ? 1 : 0;
  }
}

// ---------------- CSR build (by dst) ----------------
__global__ void k_deg(const int* __restrict__ dst, int* __restrict__ deg){
  int e = blockIdx.x*blockDim.x + threadIdx.x;
  if (e < NE) atomicAdd(&deg[dst[e]], 1);
}
__global__ void k_scan1(const int* __restrict__ deg, int* __restrict__ part){
  __shared__ int s[256];
  int t = threadIdx.x;
  int i = blockIdx.x*256 + t;
  s[t] = (i < NN) ? deg[i] : 0;
  __syncthreads();
  for (int d = 128; d > 0; d >>= 1){
    if (t < d) s[t] += s[t+d];
    __syncthreads();
  }
  if (t == 0) part[blockIdx.x] = s[0];
}
__global__ void k_scan2(int* __restrict__ part){
  __shared__ int s[256];
  int t = threadIdx.x;
  int own = (t < NPART) ? part[t] : 0;
  s[t] = own;
  __syncthreads();
  for (int d = 1; d < 256; d <<= 1){
    int v = (t >= d) ? s[t-d] : 0;
    __syncthreads();
    s[t] += v;
    __syncthreads();
  }
  if (t < NPART) part[t] = s[t] - own;   // exclusive
}
__global__ void k_scan3(const int* __restrict__ deg, const int* __restrict__ part,
                        int* __restrict__ off, int* __restrict__ cur){
  __shared__ int s[256];
  int t = threadIdx.x;
  int i = blockIdx.x*256 + t;
  int own = (i < NN) ? deg[i] : 0;
  s[t] = own;
  __syncthreads();
  for (int d = 1; d < 256; d <<= 1){
    int v = (t >= d) ? s[t-d] : 0;
    __syncthreads();
    s[t] += v;
    __syncthreads();
  }
  if (i < NN){
    int e = s[t] - own + part[blockIdx.x];
    off[i] = e; cur[i] = e;
  }
}
__global__ void k_scatter(const int* __restrict__ src, const int* __restrict__ dst,
                          int* __restrict__ cur, int* __restrict__ srcs){
  int e = blockIdx.x*blockDim.x + threadIdx.x;
  if (e < NE){
    int pos = atomicAdd(&cur[dst[e]], 1);
    srcs[pos] = src[e];
  }
}

// ---------------- weight prep: all 8 transposes in one launch (z-gridded) ----------------
struct W8 { const float* s[8]; unsigned short* d[8]; int N[8]; };
__global__ void k_w2ht8(W8 p){
  int z = blockIdx.z;
  const float* W = p.s[z]; unsigned short* Wt = p.d[z]; int N = p.N[z];
  int kb = blockIdx.x*32, nb = blockIdx.y*32;
  if (nb >= N) return;
  __shared__ float t[32][33];
  int tx = threadIdx.x & 31, ty = threadIdx.x >> 5;   // 32 x 8
  for (int r = 0; r < 32; r += 8)
    t[ty+r][tx] = W[(size_t)(kb+ty+r)*N + nb+tx];
  __syncthreads();
  for (int r = 0; r < 32; r += 8)
    Wt[(size_t)(nb+ty+r)*HD + kb+tx] = f2hu(t[tx][ty+r]);
}

// ---------------- conv1 front: h0 = (1+eps)x + agg ; also zeros stG/stT ----------------
__global__ void k_sagg_csr(const float* __restrict__ x, const int* __restrict__ off,
                           const int* __restrict__ deg, const int* __restrict__ srcs,
                           const float* __restrict__ epsp, float* __restrict__ h0,
                           float* __restrict__ z1, float* __restrict__ z2){
  int i = blockIdx.x*blockDim.x + threadIdx.x;
  if (i < 1024){ z1[i] = 0.f; z2[i] = 0.f; }
  if (i < NN){
    float s = (1.f + epsp[0]) * x[i];
    int o = off[i], d = deg[i];
    for (int j = 0; j < d; j++) s += x[srcs[o + j]];
    h0[i] = s;
  }
}

// ---------------- conv1 piecewise-linear LUT build ----------------
// A[i,k] = relu(h0[i]*w1[k] + b1[k]) is a 1-D function of scalar h0[i], so
// C[i,:] = relu(A[i,:] @ W2 + b2) is piecewise-linear in h0 with breakpoints
// t_k = -b1[k]/w1[k]. Split by sign(w1): prefix over sorted t for w1>0,
// suffix for w1<0; w1==0 constant folded into pos group at -inf.
//   C_pre[i,n] = h0*(Up[rp,n]+Un[rn,n]) + Vp[rp,n]+Vn[rn,n]   (b2 folded into Vp)
// rp = #{thrP < h0}, rn = #{thrN <= h0}.

__global__ void k_rank(const float* __restrict__ w1, const float* __restrict__ b1,
    float* __restrict__ thrP, float* __restrict__ wP, float* __restrict__ bP, int* __restrict__ idxP,
    float* __restrict__ thrN, float* __restrict__ wN, float* __restrict__ bN, int* __restrict__ idxN)
{
  __shared__ float skey[512];
  const int t = threadIdx.x;          // 512 threads; block 0 = pos, block 1 = neg
  const bool neg = (blockIdx.x == 1);
  const float w = w1[t], b = b1[t];
  const float INF = __builtin_inff();
  float key;
  if (!neg) key = (w > 0.f) ? (-b/w) : ((w == 0.f) ? -INF : INF);
  else      key = (w < 0.f) ? (-b/w) : -INF;
  skey[t] = key;
  __syncthreads();
  int r = 0;
  for (int j = 0; j < 512; j++){
    float kj = skey[j];
    r += (kj < key || (kj == key && j < t)) ? 1 : 0;
  }
  if (!neg){
    thrP[r] = key; idxP[r] = t;
    wP[r] = (w > 0.f) ? w : 0.f;
    bP[r] = (w > 0.f) ? b : ((w == 0.f) ? fmaxf(b, 0.f) : 0.f);
  } else {
    thrN[r] = key; idxN[r] = t;
    wN[r] = (w < 0.f) ? w : 0.f;
    bN[r] = (w < 0.f) ? b : 0.f;
  }
}

// grid dim3(32 /*chunk*/, 2 /*0=pos,1=neg*/), 512 threads (one per output col n)
__global__ void k_pref_chunks(const float* __restrict__ W2,
    const int* __restrict__ idxP, const float* __restrict__ wP, const float* __restrict__ bP,
    const int* __restrict__ idxN, const float* __restrict__ wN, const float* __restrict__ bN,
    float* __restrict__ CU, float* __restrict__ CV)   // [2][32][512]
{
  __shared__ float sw[16], sb[16];
  __shared__ int si[16];
  const int n = threadIdx.x;
  const int c = blockIdx.x;
  const bool neg = (blockIdx.y == 1);
  if (n < 16){
    int j = c*16 + n;
    sw[n] = neg ? wN[j] : wP[j];
    sb[n] = neg ? bN[j] : bP[j];
    si[n] = neg ? idxN[j] : idxP[j];
  }
  __syncthreads();
  float aU = 0.f, aV = 0.f;
  #pragma unroll
  for (int k = 0; k < 16; k++){
    float v = W2[(size_t)si[k]*HD + n];
    aU = fmaf(sw[k], v, aU);
    aV = fmaf(sb[k], v, aV);
  }
  size_t o = ((size_t)blockIdx.y*32 + c)*HD + n;
  CU[o] = aU; CV[o] = aV;
}

// grid dim3(32, 2), 512 threads: base from chunk sums, then emit 16 table rows
__global__ void k_pref_write(const float* __restrict__ W2, const float* __restrict__ b2,
    const int* __restrict__ idxP, const float* __restrict__ wP, const float* __restrict__ bP,
    const int* __restrict__ idxN, const float* __restrict__ wN, const float* __restrict__ bN,
    const float* __restrict__ CU, const float* __restrict__ CV,
    float* __restrict__ Up, float* __restrict__ Vp,
    float* __restrict__ Un, float* __restrict__ Vn)
{
  __shared__ float sw[16], sb[16];
  __shared__ int si[16];
  const int n = threadIdx.x;
  const int c = blockIdx.x;
  const bool neg = (blockIdx.y == 1);
  if (n < 16){
    int j = c*16 + n;
    sw[n] = neg ? wN[j] : wP[j];
    sb[n] = neg ? bN[j] : bP[j];
    si[n] = neg ? idxN[j] : idxP[j];
  }
  __syncthreads();
  float aU = 0.f, aV = 0.f;
  if (!neg){
    aV = b2[n];                               // fold b2 into Vp (all rows)
    for (int cc = 0; cc < c; cc++){
      size_t o = (size_t)cc*HD + n;
      aU += CU[o]; aV += CV[o];
    }
    if (c == 0){ Up[n] = 0.f; Vp[n] = aV; }   // row 0: nothing active
    #pragma unroll
    for (int k = 0; k < 16; k++){
      float v = W2[(size_t)si[k]*HD + n];
      aU = fmaf(sw[k], v, aU);
      aV = fmaf(sb[k], v, aV);
      size_t r = (size_t)(c*16 + k + 1);
      Up[r*HD + n] = aU;
      Vp[r*HD + n] = aV;
    }
  } else {
    for (int cc = c+1; cc < 32; cc++){
      size_t o = ((size_t)32 + cc)*HD + n;
      aU += CU[o]; aV += CV[o];
    }
    if (c == 31){ Un[(size_t)512*HD + n] = 0.f; Vn[(size_t)512*HD + n] = 0.f; }  // empty suffix
    #pragma unroll
    for (int k = 15; k >= 0; k--){
      float v = W2[(size_t)si[k]*HD + n];
      aU = fmaf(sw[k], v, aU);
      aV = fmaf(sb[k], v, aV);
      size_t r = (size_t)(c*16 + k);
      Un[r*HD + n] = aU;
      Vn[r*HD + n] = aV;
    }
  }
}

// ---------------- conv1 via LUT ----------------
__global__ __launch_bounds__(256) void k_conv1_lut(const float* __restrict__ h0,
    const float* __restrict__ thrP, const float* __restrict__ thrN,
    const float* __restrict__ Up, const float* __restrict__ Vp,
    const float* __restrict__ Un, const float* __restrict__ Vn,
    _Float16* __restrict__ C, float* __restrict__ st)
{
  __shared__ float ls[2048], lq[2048];
  const int tid = threadIdx.x;
  const int wave = tid >> 6, lane = tid & 63;
  const int c0 = lane << 3;
  float tP[8], tN[8];
  #pragma unroll
  for (int k = 0; k < 8; k++){ tP[k] = thrP[c0+k]; tN[k] = thrN[c0+k]; }
  float s8[8] = {}, q8[8] = {};
  for (int r = blockIdx.x*4 + wave; r < NN; r += gridDim.x*4){
    float h0v = h0[r];
    int cnt = 0;                        // rp in high 16 bits, rn in low 16 (each <= 512)
    #pragma unroll
    for (int k = 0; k < 8; k++){
      cnt += (tP[k] <  h0v) ? 0x10000 : 0;
      cnt += (tN[k] <= h0v) ? 1 : 0;
    }
    #pragma unroll
    for (int off = 1; off < 64; off <<= 1) cnt += __shfl_xor(cnt, off);
    const int rp = cnt >> 16, rn = cnt & 0xFFFF;
    const float4* up = (const float4*)(Up + ((size_t)rp << 9) + c0);
    const float4* vp = (const float4*)(Vp + ((size_t)rp << 9) + c0);
    const float4* un = (const float4*)(Un + ((size_t)rn << 9) + c0);
    const float4* vn = (const float4*)(Vn + ((size_t)rn << 9) + c0);
    float4 ua = up[0], ub = up[1];
    float4 pa = vp[0], pb = vp[1];
    float4 na = un[0], nb = un[1];
    float4 ma = vn[0], mb = vn[1];
    float v[8];
    v[0] = fmaf(h0v, ua.x + na.x, pa.x + ma.x);
    v[1] = fmaf(h0v, ua.y + na.y, pa.y + ma.y);
    v[2] = fmaf(h0v, ua.z + na.z, pa.z + ma.z);
    v[3] = fmaf(h0v, ua.w + na.w, pa.w + ma.w);
    v[4] = fmaf(h0v, ub.x + nb.x, pb.x + mb.x);
    v[5] = fmaf(h0v, ub.y + nb.y, pb.y + mb.y);
    v[6] = fmaf(h0v, ub.z + nb.z, pb.z + mb.z);
    v[7] = fmaf(h0v, ub.w + nb.w, pb.w + mb.w);
    half8 hv;
    #pragma unroll
    for (int k = 0; k < 8; k++){
      float t = v[k] > 0.f ? v[k] : 0.f;
      hv[k] = (_Float16)t;
      s8[k] += t; q8[k] += t*t;
    }
    ((half8*)C)[(size_t)r*64 + lane] = hv;
  }
  #pragma unroll
  for (int k = 0; k < 8; k++){
    ls[wave*512 + c0 + k] = s8[k];
    lq[wave*512 + c0 + k] = q8[k];
  }
  __syncthreads();
  for (int cc = tid; cc < 512; cc += 256){
    float S = ls[cc] + ls[512+cc] + ls[1024+cc] + ls[1536+cc];
    float Q = lq[cc] + lq[512+cc] + lq[1024+cc] + lq[1536+cc];
    unsafeAtomicAdd(&st[cc], S);
    unsafeAtomicAdd(&st[HD+cc], Q);
  }
}

// ---------------- gather+combine v2: 2 rows/wave x 2-edge unroll (MLP) ----------------
__global__ __launch_bounds__(256) void k_agg_csr(const _Float16* __restrict__ T,
                          const int* __restrict__ off,
                          const int* __restrict__ deg, const int* __restrict__ srcs,
                          const float* __restrict__ epsp,
                          const float* __restrict__ st, const float* __restrict__ g,
                          const float* __restrict__ bb, _Float16* __restrict__ G,
                          float* __restrict__ stGz){
  const int tid = threadIdx.x;
  const int wave = tid >> 6, t = tid & 63;
  if (blockIdx.x == 0){
    for (int c = tid; c < 1024; c += 256) stGz[c] = 0.f;
  }
  const int i0 = blockIdx.x*8 + wave*2;
  if (i0 >= NN) return;
  const int i1 = i0 + 1;
  const bool ok1 = (i1 < NN);
  const int i1c = ok1 ? i1 : i0;
  const int c0 = t << 3;
  const float inv_n = 1.f/(float)NN;
  float sc[8], sh[8];
  #pragma unroll
  for (int k = 0; k < 8; k++){
    int c = c0 + k;
    float mu = st[c]*inv_n;
    float var = st[HD+c]*inv_n - mu*mu;
    float s = g[c]*rsqrtf(var+BN_EPS);
    sc[k] = s; sh[k] = bb[c] - mu*s;
  }
  const half8* Tv = (const half8*)T;
  half8 p0 = Tv[(size_t)i0*64 + t];
  half8 p1 = Tv[(size_t)i1c*64 + t];
  const float ep = 1.f + epsp[0];
  const int o0 = off[i0], d0 = deg[i0];
  const int o1 = off[i1c], d1 = deg[i1c];
  float a0[8], a1[8];
  #pragma unroll
  for (int k = 0; k < 8; k++){ a0[k] = (float)p0[k] * ep; a1[k] = (float)p1[k] * ep; }
  const int jm = d0 > d1 ? d0 : d1;
  int j = 0;
  for (; j + 1 < jm; j += 2){
    int s0a = (j     < d0) ? srcs[o0 + j]     : i0;
    int s0b = (j + 1 < d0) ? srcs[o0 + j + 1] : i0;
    int s1a = (j     < d1) ? srcs[o1 + j]     : i1c;
    int s1b = (j + 1 < d1) ? srcs[o1 + j + 1] : i1c;
    half8 q0a = Tv[(size_t)s0a*64 + t];
    half8 q0b = Tv[(size_t)s0b*64 + t];
    half8 q1a = Tv[(size_t)s1a*64 + t];
    half8 q1b = Tv[(size_t)s1b*64 + t];
    if (j < d0){
      #pragma unroll
      for (int k = 0; k < 8; k++) a0[k] += (float)q0a[k];
      if (j + 1 < d0){
        #pragma unroll
        for (int k = 0; k < 8; k++) a0[k] += (float)q0b[k];
      }
    }
    if (j < d1){
      #pragma unroll
      for (int k = 0; k < 8; k++) a1[k] += (float)q1a[k];
      if (j + 1 < d1){
        #pragma unroll
        for (int k = 0; k < 8; k++) a1[k] += (float)q1b[k];
      }
    }
  }
  if (j < jm){
    int s0a = (j < d0) ? srcs[o0 + j] : i0;
    int s1a = (j < d1) ? srcs[o1 + j] : i1c;
    half8 q0a = Tv[(size_t)s0a*64 + t];
    half8 q1a = Tv[(size_t)s1a*64 + t];
    if (j < d0){
      #pragma unroll
      for (int k = 0; k < 8; k++) a0[k] += (float)q0a[k];
    }
    if (j < d1){
      #pragma unroll
      for (int k = 0; k < 8; k++) a1[k] += (float)q1a[k];
    }
  }
  {
    float cnt0 = ep + (float)d0;
    half8 r0;
    #pragma unroll
    for (int k = 0; k < 8; k++) r0[k] = (_Float16)fmaf(sc[k], a0[k], cnt0*sh[k]);
    ((half8*)G)[(size_t)i0*64 + t] = r0;
  }
  if (ok1){
    float cnt1 = ep + (float)d1;
    half8 r1;
    #pragma unroll
    for (int k = 0; k < 8; k++) r1[k] = (_Float16)fmaf(sc[k], a1[k], cnt1*sh[k]);
    ((half8*)G)[(size_t)i1*64 + t] = r1;
  }
}

// ---------------- MFMA GEMM v6: persistent 2-tiles-per-block (grid 784) ----------------
// r10 plateau test: grid was 1568 blocks vs ~1280 resident slots -> 1.22-round dispatch
// with a ~288-block drain tail + 1568 cold prologues. Persistent form: 784 blocks, each
// runs tiles F and F+784 (perfect balance; 784 % 8 == 0 preserves XCD swizzle slot).
// Pipeline/epilogue identical to r8's k_gemm5 (51.4us, VGPR 64). vmcnt across the rep
// boundary is safe: counts retire in issue order, so epilogue stores ahead of the next
// rep's stage loads only make vmcnt(4) more conservative.
template<bool STATS>
__global__ __launch_bounds__(256, 4) void k_gemm6(const _Float16* __restrict__ A,
    const _Float16* __restrict__ Wt, const float* __restrict__ bias,
    _Float16* __restrict__ C, float* __restrict__ st, float* __restrict__ zbuf, int M)
{
  constexpr int BK = 32;
  constexpr int TS = 128*BK;                 // 4096 halves = 8KB per matrix per buffer
  __shared__ __attribute__((aligned(16))) _Float16 pool[4*TS];   // 2 x (A,B) = 32KB
  const int tid = threadIdx.x;
  if (zbuf && blockIdx.x == 0){
    for (int c = tid; c < 1024; c += 256) zbuf[c] = 0.f;
  }
  const int Mb = (M + 127) >> 7;
  const int QB = (Mb + 7) >> 3;
  const int FT = 8*4*QB;                     // 1568 flat tiles
  const int w = tid >> 6, lane = tid & 63;
  const int wm = (w >> 1) << 6, wn = (w & 1) << 6;
  const int quad = lane >> 4, l16 = lane & 15;

  for (int rep = 0; rep < 2; rep++){
    const int F = blockIdx.x + rep*784;
    if (F >= FT) break;
    const int S = F & 7, rr = F >> 3;
    const int bx = rr & 3, q = rr >> 2;
    const int by = q*8 + S;
    if (by >= Mb) continue;                  // block-uniform skip
    const int m0 = by * 128, n0 = bx * 128;

    floatx4 acc[4][4] = {};

    // staging: tile = 128 rows x 32 halves = 512 chunks of 16B; thread covers {tid, 256+tid}.
    const _Float16 *ga[2], *gb[2];
    #pragma unroll
    for (int j = 0; j < 2; j++){
      int c = j*256 + tid;
      int row = c >> 2, kc = (c & 3) << 3;
      int rA = m0 + row; if (rA > M-1) rA = M-1;
      ga[j] = A  + (size_t)rA*HD + kc;
      gb[j] = Wt + (size_t)(n0 + row)*HD + kc;
    }

    auto stage = [&](int kt, int buf){
      _Float16* As = pool + buf*2*TS;
      _Float16* Bs = As + TS;
      #pragma unroll
      for (int j = 0; j < 2; j++){
        const int lb = (j*256 + w*64)*8;     // wave-uniform dest base (chunks) * 8 halves
        gload16(ga[j] + kt*BK, As + lb);
        gload16(gb[j] + kt*BK, Bs + lb);
      }
    };

    stage(0, 0);                             // 4 vmem/thread in flight
    stage(1, 1);                             // 8 in flight
    #pragma unroll
    for (int kt = 0; kt < 16; kt++){
      __builtin_amdgcn_sched_barrier(0);     // pin iteration boundary (vmcnt bookkeeping)
      if (kt == 15) asm volatile("s_waitcnt vmcnt(0)" ::: "memory");
      else          asm volatile("s_waitcnt vmcnt(4)" ::: "memory");  // tile kt landed; kt+1 in flight
      __builtin_amdgcn_s_barrier();          // everyone's tile-kt portion landed
      __builtin_amdgcn_sched_barrier(0);
      const _Float16* As = pool + (kt & 1)*2*TS;
      const _Float16* Bs = As + TS;
      half8 af[4], bf[4];
      #pragma unroll
      for (int t4 = 0; t4 < 4; t4++){
        af[t4] = *(const half8*)(As + (wm + t4*16 + l16)*BK + quad*8);
        bf[t4] = *(const half8*)(Bs + (wn + t4*16 + l16)*BK + quad*8);
      }
      #pragma unroll
      for (int mi = 0; mi < 4; mi++){
        #pragma unroll
        for (int ni = 0; ni < 4; ni++){
          acc[mi][ni] = __builtin_amdgcn_mfma_f32_16x16x32_f16(af[mi], bf[ni], acc[mi][ni], 0, 0, 0);
        }
      }
      __builtin_amdgcn_sched_barrier(0);     // ds_reads stay before the WAR barrier
      __builtin_amdgcn_s_barrier();          // all waves done reading buf (kt&1)
      __builtin_amdgcn_sched_barrier(0);
      if (kt < 14) stage(kt+2, kt & 1);      // overwrite now-safe buffer; stays in flight
    }
    __syncthreads();                         // full drain before pool reuse

    // epilogue: bias+relu (+stats); D bounced through pool in two 64-row passes (CP=136)
    constexpr int CP = 136;
    _Float16* Ds = pool;                     // 64*136 = 8704 halves <= 16384 pool
    float bs4[4];
    #pragma unroll
    for (int ni = 0; ni < 4; ni++) bs4[ni] = bias[n0 + wn + ni*16 + l16];
    float sv[4] = {0,0,0,0}, qv[4] = {0,0,0,0};
    #pragma unroll
    for (int half = 0; half < 2; half++){
      const int hb = half << 6;              // 0 or 64
      if (wm == hb){
        #pragma unroll
        for (int ni = 0; ni < 4; ni++){
          int ccol = wn + ni*16 + l16;
          #pragma unroll
          for (int mi = 0; mi < 4; mi++){
            #pragma unroll
            for (int reg = 0; reg < 4; reg++){
              int row_l = wm + mi*16 + quad*4 + reg;
              float v = acc[mi][ni][reg] + bs4[ni];
              v = v > 0.f ? v : 0.f;
              Ds[(row_l - hb)*CP + ccol] = (_Float16)v;
              if (STATS && (m0 + row_l < M)){ sv[ni] += v; qv[ni] += v*v; }
            }
          }
        }
      }
      __syncthreads();
      #pragma unroll
      for (int s = 0; s < 4; s++){
        int chunk = tid + s*256;      // 0..1023: 64 rows x 16 col-chunks
        int row_l = chunk >> 4;
        int colc  = (chunk & 15) << 3;
        int r = m0 + hb + row_l;
        if (r < M)
          *(half8*)&C[(size_t)r*HD + n0 + colc] = *(const half8*)&Ds[row_l*CP + colc];
      }
      __syncthreads();                       // Ds reads done; safe for next rep's staging
    }
    if (STATS){
      #pragma unroll
      for (int ni = 0; ni < 4; ni++){
        float s = sv[ni], qq = qv[ni];
        s += __shfl_xor(s, 16); s += __shfl_xor(s, 32);
        qq += __shfl_xor(qq, 16); qq += __shfl_xor(qq, 32);
        if (quad == 0){
          int ccol = n0 + wn + ni*16 + l16;
          unsafeAtomicAdd(&st[ccol], s);
          unsafeAtomicAdd(&st[HD+ccol], qq);
        }
      }
    }
  }
}

// ---------------- head prep: fold last BN affine into lin1 weights; init mx/mn ----------------
__global__ void k_headprep(const unsigned short* __restrict__ w1t, const float* __restrict__ b1,
    const float* __restrict__ st, const float* __restrict__ g, const float* __restrict__ bb,
    unsigned short* __restrict__ w1s, float* __restrict__ b1p,
    unsigned* __restrict__ mx, unsigned* __restrict__ mn){
  int n = blockIdx.x; int t = threadIdx.x;
  if (n == 0 && t < 64){ mx[t] = 0u; }
  if (n == 1 && t < 64){ mn[t] = 0xFFFFFFFFu; }
  __shared__ float red[256];
  const float inv_n = 1.f/(float)NN;
  float acc = 0.f;
  #pragma unroll
  for (int kk = 0; kk < 2; kk++){
    int k = t + kk*256;
    float mu = st[k]*inv_n;
    float var = st[HD+k]*inv_n - mu*mu;
    float sc = g[k]*rsqrtf(var+BN_EPS);
    float sh = bb[k] - mu*sc;
    float wv = h2fu(w1t[(size_t)n*HD + k]);
    w1s[(size_t)n*HD + k] = f2hu(sc*wv);
    acc += sh*wv;
  }
  red[t] = acc; __syncthreads();
  for (int d = 128; d > 0; d >>= 1){ if (t < d) red[t] += red[t+d]; __syncthreads(); }
  if (t == 0) b1p[n] = b1[n] + red[0];
}

// ---------------- fused head (pipelined) with per-block LDS min/max reduction ----------------
__global__ __launch_bounds__(256) void k_head(const _Float16* __restrict__ Xh,
    const _Float16* __restrict__ W1t, const float* __restrict__ b1,
    const float* __restrict__ w2, const float* __restrict__ b2p,
    const int* __restrict__ mask, const int* __restrict__ batch,
    float* __restrict__ z2, unsigned* __restrict__ mx, unsigned* __restrict__ mn, int M)
{
  constexpr int PK = 72;
  __shared__ __attribute__((aligned(16))) _Float16 As[128*PK];
  __shared__ __attribute__((aligned(16))) _Float16 Bs[64*PK];
  __shared__ unsigned smx[64], smn[64];
  const int tid = threadIdx.x;
  const int m0 = blockIdx.x * 128;
  const int w = tid >> 6, lane = tid & 63;
  const int wm = w << 5;
  const int quad = lane >> 4, l16 = lane & 15;

  if (tid < 64){ smx[tid] = 0u; smn[tid] = 0xFFFFFFFFu; }

  floatx4 acc[2][4] = {};

  const int srow = tid >> 1;
  const int skoff = (tid & 1) << 5;
  int arow = m0 + srow; if (arow > M-1) arow = M-1;
  const _Float16* Ag = Xh + (size_t)arow*HD + skoff;
  _Float16* Asw = As + srow*PK + skoff;
  const int brow = tid >> 2;
  const int bkoff = (tid & 3) << 4;
  const _Float16* Bg = W1t + (size_t)brow*HD + bkoff;
  _Float16* Bsw = Bs + brow*PK + bkoff;

  half8 ca[4], cb[2], na[4], nb[2];
  #pragma unroll
  for (int j = 0; j < 4; j++) ca[j] = *(const half8*)(Ag + j*8);
  cb[0] = *(const half8*)(Bg); cb[1] = *(const half8*)(Bg + 8);

  #pragma unroll
  for (int kt = 0; kt < HD; kt += 64){
    __syncthreads();
    #pragma unroll
    for (int j = 0; j < 4; j++) *(half8*)(Asw + j*8) = ca[j];
    *(half8*)(Bsw) = cb[0]; *(half8*)(Bsw + 8) = cb[1];
    if (kt + 64 < HD){
      #pragma unroll
      for (int j = 0; j < 4; j++) na[j] = *(const half8*)(Ag + kt + 64 + j*8);
      nb[0] = *(const half8*)(Bg + kt + 64); nb[1] = *(const half8*)(Bg + kt + 72);
    }
    __syncthreads();
    #pragma unroll
    for (int k0 = 0; k0 < 64; k0 += 32){
      half8 af[2], bf[4];
      #pragma unroll
      for (int mi = 0; mi < 2; mi++) af[mi] = *(const half8*)&As[(wm + mi*16 + l16)*PK + k0 + quad*8];
      #pragma unroll
      for (int ni = 0; ni < 4; ni++) bf[ni] = *(const half8*)&Bs[(ni*16 + l16)*PK + k0 + quad*8];
      #pragma unroll
      for (int mi = 0; mi < 2; mi++){
        #pragma unroll
        for (int ni = 0; ni < 4; ni++){
          acc[mi][ni] = __builtin_amdgcn_mfma_f32_16x16x32_f16(af[mi], bf[ni], acc[mi][ni], 0, 0, 0);
        }
      }
    }
    #pragma unroll
    for (int j = 0; j < 4; j++) ca[j] = na[j];
    cb[0] = nb[0]; cb[1] = nb[1];
  }

  float b1v[4], w2v[4];
  #pragma unroll
  for (int ni = 0; ni < 4; ni++){ b1v[ni] = b1[ni*16 + l16]; w2v[ni] = w2[ni*16 + l16]; }
  const float b2 = b2p[0];
  #pragma unroll
  for (int mi = 0; mi < 2; mi++){
    #pragma unroll
    for (int reg = 0; reg < 4; reg++){
      int r = m0 + wm + mi*16 + quad*4 + reg;
      bool ok = r < M;
      float mk = (ok && mask[r]) ? 1.f : 0.f;
      float t = 0.f;
      #pragma unroll
      for (int ni = 0; ni < 4; ni++){
        float v = leaky(acc[mi][ni][reg] + b1v[ni]) * mk;
        t += v * w2v[ni];
      }
      t += __shfl_xor(t, 1); t += __shfl_xor(t, 2);
      t += __shfl_xor(t, 4); t += __shfl_xor(t, 8);
      if (l16 == 0 && ok){
        float zv = leaky(t + b2) * mk;
        z2[r] = zv;
        unsigned u = __float_as_uint(zv);
        unsigned key = (u & 0x80000000u) ? ~u : (u | 0x80000000u);
        int gg = batch[r];
        atomicMax(&smx[gg], key); atomicMin(&smn[gg], key);
      }
    }
  }
  __syncthreads();
  if (tid < 64){
    unsigned vx = smx[tid], vn = smn[tid];
    if (vx != 0u)          atomicMax(&mx[tid], vx);
    if (vn != 0xFFFFFFFFu) atomicMin(&mn[tid], vn);
  }
}

// ---------------- BN apply v3: 4 rows/wave for MLP ----------------
template<bool RESID>
__global__ __launch_bounds__(256) void k_bn_apply_stats(const uint4* __restrict__ Hu,
    const float* __restrict__ g, const float* __restrict__ bb, const float* __restrict__ st,
    const uint4* __restrict__ Pu, const float* __restrict__ stP,
    const float* __restrict__ gP, const float* __restrict__ bP,
    const int* __restrict__ mask, const float* __restrict__ invs,
    uint4* __restrict__ Tu, float* __restrict__ st2)
{
  __shared__ float ls[2048], lq[2048];
  const int tid = threadIdx.x;
  const int wave = tid >> 6, lane = tid & 63;
  const int c8 = lane << 3;
  const float inv_n = 1.f/(float)NN;
  float sc[8], sh[8], pc[8], ps[8];
  #pragma unroll
  for (int k = 0; k < 8; k++){
    int c = c8 + k;
    float mu = st[c]*inv_n;
    float var = st[HD+c]*inv_n - mu*mu;
    float s = g[c]*rsqrtf(var+BN_EPS);
    sc[k] = s; sh[k] = bb[c] - mu*s;
    if (RESID){
      float muP = stP[c]*inv_n;
      float varP = stP[HD+c]*inv_n - muP*muP;
      float sP = gP[c]*rsqrtf(varP+BN_EPS);
      pc[k] = sP; ps[k] = bP[c] - muP*sP;
    }
  }
  float s8[8] = {}, q8[8] = {};

  auto proc = [&](uint4 u, uint4 p, float ww, int r, bool ok){
    if (!ok) return;
    float hv[8];
    hv[0]=h2fu(u.x&0xFFFF); hv[1]=h2fu(u.x>>16);
    hv[2]=h2fu(u.y&0xFFFF); hv[3]=h2fu(u.y>>16);
    hv[4]=h2fu(u.z&0xFFFF); hv[5]=h2fu(u.z>>16);
    hv[6]=h2fu(u.w&0xFFFF); hv[7]=h2fu(u.w>>16);
    float v[8];
    #pragma unroll
    for (int k = 0; k < 8; k++) v[k] = leaky(fmaf(hv[k], sc[k], sh[k]));
    if (RESID){
      float pv[8];
      pv[0]=h2fu(p.x&0xFFFF); pv[1]=h2fu(p.x>>16);
      pv[2]=h2fu(p.y&0xFFFF); pv[3]=h2fu(p.y>>16);
      pv[4]=h2fu(p.z&0xFFFF); pv[5]=h2fu(p.z>>16);
      pv[6]=h2fu(p.w&0xFFFF); pv[7]=h2fu(p.w>>16);
      #pragma unroll
      for (int k = 0; k < 8; k++) v[k] += fmaf(pv[k], pc[k], ps[k]);
    }
    uint4 o;
    o.x = packh2(v[0]*ww, v[1]*ww); o.y = packh2(v[2]*ww, v[3]*ww);
    o.z = packh2(v[4]*ww, v[5]*ww); o.w = packh2(v[6]*ww, v[7]*ww);
    Tu[(size_t)r*64 + lane] = o;
    #pragma unroll
    for (int k = 0; k < 8; k++){ float t = v[k]*ww; s8[k] += t; q8[k] += t*t; }
  };

  for (int r0 = blockIdx.x*16 + wave*4; r0 < NN; r0 += gridDim.x*16){
    const int r1 = r0 + 1, r2 = r0 + 2, r3 = r0 + 3;
    const bool ok1 = r1 < NN, ok2 = r2 < NN, ok3 = r3 < NN;
    const int r1c = ok1 ? r1 : r0, r2c = ok2 ? r2 : r0, r3c = ok3 ? r3 : r0;
    uint4 u0 = Hu[(size_t)r0*64 + lane];
    uint4 u1 = Hu[(size_t)r1c*64 + lane];
    uint4 u2 = Hu[(size_t)r2c*64 + lane];
    uint4 u3 = Hu[(size_t)r3c*64 + lane];
    uint4 p0{}, p1{}, p2{}, p3{};
    if (RESID){
      p0 = Pu[(size_t)r0*64 + lane];
      p1 = Pu[(size_t)r1c*64 + lane];
      p2 = Pu[(size_t)r2c*64 + lane];
      p3 = Pu[(size_t)r3c*64 + lane];
    }
    float ww0 = mask[r0]  ? invs[r0]  : 0.f;
    float ww1 = mask[r1c] ? invs[r1c] : 0.f;
    float ww2 = mask[r2c] ? invs[r2c] : 0.f;
    float ww3 = mask[r3c] ? invs[r3c] : 0.f;
    proc(u0, p0, ww0, r0, true);
    proc(u1, p1, ww1, r1, ok1);
    proc(u2, p2, ww2, r2, ok2);
    proc(u3, p3, ww3, r3, ok3);
  }
  #pragma unroll
  for (int k = 0; k < 8; k++){
    ls[wave*512 + c8 + k] = s8[k];
    lq[wave*512 + c8 + k] = q8[k];
  }
  __syncthreads();
  for (int cc = tid; cc < 512; cc += 256){
    float S = ls[cc] + ls[512+cc] + ls[1024+cc] + ls[1536+cc];
    float Q = lq[cc] + lq[512+cc] + lq[1024+cc] + lq[1536+cc];
    unsafeAtomicAdd(&st2[cc], S);
    unsafeAtomicAdd(&st2[HD+cc], Q);
  }
}

// ---------------- final normalize ----------------
__device__ __forceinline__ float funkey(unsigned k){
  unsigned u = (k & 0x80000000u) ? (k & 0x7fffffffu) : ~k;
  return __uint_as_float(u);
}
__global__ void k_final(const float* __restrict__ z2, const int* __restrict__ batch,
                        const unsigned* __restrict__ mx, const unsigned* __restrict__ mn,
                        float* __restrict__ out){
  int i = blockIdx.x*blockDim.x + threadIdx.x;
  if (i < NN){
    int g = batch[i];
    float bmax = funkey(mx[g]), bmin = funkey(mn[g]);
    out[i] = (z2[i] - bmin) / ((bmax + 1e-6f) - bmin);
  }
}

extern "C" void kernel_launch(void* const* d_in, const int* in_sizes, int n_in,
                              void* d_out, int out_size, void* d_ws, size_t ws_size,
                              hipStream_t stream)
{
  const float* x      = (const float*)d_in[0];
  const int*   ei     = (const int*)d_in[1];
  const int*   src    = ei;
  const int*   dst    = ei + NE;
  const int*   batch  = (const int*)d_in[2];
  const float* c1_w1  = (const float*)d_in[3];
  const float* c1_b1  = (const float*)d_in[4];
  const float* c1_w2  = (const float*)d_in[5];
  const float* c1_b2  = (const float*)d_in[6];
  const float* c1_bng = (const float*)d_in[7];
  const float* c1_bnb = (const float*)d_in[8];
  const float* eps1   = (const float*)d_in[9];
  const float* bn1_g  = (const float*)d_in[10];
  const float* bn1_b  = (const float*)d_in[11];
  const float* cw1    = (const float*)d_in[12];
  const float* cb1    = (const float*)d_in[13];
  const float* cw2    = (const float*)d_in[14];
  const float* cb2    = (const float*)d_in[15];
  const float* cbn_g  = (const float*)d_in[16];
  const float* cbn_b  = (const float*)d_in[17];
  const float* ceps   = (const float*)d_in[18];
  const float* bns_g  = (const float*)d_in[19];
  const float* bns_b  = (const float*)d_in[20];
  const float* l1_w   = (const float*)d_in[21];
  const float* l1_b   = (const float*)d_in[22];
  const float* l2_w   = (const float*)d_in[23];
  const float* l2_b   = (const float*)d_in[24];
  float* out = (float*)d_out;

  const size_t NH = (size_t)NN*HD;
  unsigned short* buf0 = (unsigned short*)d_ws;   // fp16 NH
  unsigned short* buf1 = buf0 + NH;               // fp16 NH
  unsigned short* buf2 = buf1 + NH;               // fp16 NH
  float* h0   = (float*)(buf2 + NH);              // NN
  float* invs = h0 + NN;                          // NN
  float* z2   = invs + NN;                        // NN
  float* stG  = z2 + NN;                          // 1024
  float* stT  = stG + 1024;                       // 4 x 1024
  unsigned* mx = (unsigned*)(stT + 4*1024);       // 64
  unsigned* mn = mx + 64;                         // 64
  float* b1p  = (float*)(mn + 64);                // 64
  int* part = (int*)(b1p + 64);                   // 256 (scan partials)
  int* deg  = part + 256;                         // NN
  int* off  = deg + NN;                           // NN
  int* cur  = off + NN;                           // NN
  int* srcs = cur + NN;                           // NE
  int* m[5];
  m[0] = srcs + NE;
  for (int k=1;k<5;k++) m[k] = m[k-1] + NN;
  unsigned short* wt[7];
  wt[0] = (unsigned short*)(m[4] + NN);
  for (int k=1;k<7;k++) wt[k] = wt[k-1] + HD*HD;
  unsigned short* w1t = wt[6] + HD*HD;            // 64*512 fp16
  unsigned short* w1s = w1t + (size_t)HIDN*HD;    // 64*512 fp16 (affine-folded)

  // conv1 LUT tables live in buf1 (dead until first k_agg_csr writes Q=buf1)
  float* tab  = (float*)buf1;
  float* thrP = tab;                              // 512
  float* wPs  = thrP + 512;
  float* bPs  = wPs + 512;
  float* thrN = bPs + 512;
  float* wNs  = thrN + 512;
  float* bNs  = wNs + 512;
  int*   idxP = (int*)(bNs + 512);                // 512
  int*   idxN = idxP + 512;                       // 512
  float* Up   = (float*)(idxN + 512);             // 513*512
  float* Vp   = Up + 513*512;
  float* Un   = Vp + 513*512;
  float* Vn   = Un + 513*512;
  float* CU   = Vn + 513*512;                     // [2][32][512] chunk sums
  float* CV   = CU + 2*32*512;                    // total ~4.5 MB << 51.2 MB

  const int TPB = 256;
  dim3 gN((NN+TPB-1)/TPB);
  dim3 gE((NE+TPB-1)/TPB);
  dim3 gmfma(784);                      // persistent: each block runs tiles F and F+784
  dim3 ghead((NN+127)/128);
  dim3 gagg((NN+7)/8);                  // 2 rows/wave

  // setup
  k_invs_mask0<<<gN, TPB, 0, stream>>>(batch, x, invs, m[0], deg);
  // CSR by dst (parallel 3-phase scan)
  k_deg<<<gE,TPB,0,stream>>>(dst, deg);
  k_scan1<<<NPART,256,0,stream>>>(deg, part);
  k_scan2<<<1,256,0,stream>>>(part);
  k_scan3<<<NPART,256,0,stream>>>(deg, part, off, cur);
  k_scatter<<<gE,TPB,0,stream>>>(src, dst, cur, srcs);
  // masks via CSR gather
  for (int k=1;k<5;k++)
    k_mask_gather<<<gN,TPB,0,stream>>>(m[k-1], m[k], off, deg, srcs);
  // weight prep: all 8 transposes in one launch
  W8 wp;
  wp.s[0] = c1_w2; wp.d[0] = wt[0]; wp.N[0] = HD;
  for (int i=0;i<3;i++){
    wp.s[1+i] = cw1 + (size_t)i*HD*HD; wp.d[1+i] = wt[1+i]; wp.N[1+i] = HD;
    wp.s[4+i] = cw2 + (size_t)i*HD*HD; wp.d[4+i] = wt[4+i]; wp.N[4+i] = HD;
  }
  wp.s[7] = l1_w; wp.d[7] = w1t; wp.N[7] = HIDN;
  k_w2ht8<<<dim3(HD/32, HD/32, 8),256,0,stream>>>(wp);

  // conv1 LUT build: parallel rank-sort + chunked prefix/suffix tables
  k_rank<<<2,512,0,stream>>>(c1_w1, c1_b1, thrP, wPs, bPs, idxP, thrN, wNs, bNs, idxN);
  k_pref_chunks<<<dim3(32,2),512,0,stream>>>(c1_w2, idxP, wPs, bPs, idxN, wNs, bNs, CU, CV);
  k_pref_write<<<dim3(32,2),512,0,stream>>>(c1_w2, c1_b2, idxP, wPs, bPs, idxN, wNs, bNs,
                                            CU, CV, Up, Vp, Un, Vn);

  // conv1: h0 (zeros stG,stT[0]), LUT lookup(+stats)->buf2, apply<false>->buf0
  k_sagg_csr<<<gN,TPB,0,stream>>>(x, off, deg, srcs, eps1, h0, stG, stT);
  k_conv1_lut<<<512,256,0,stream>>>(h0, thrP, thrN, Up, Vp, Un, Vn, (_Float16*)buf2, stG);
  k_bn_apply_stats<false><<<512,256,0,stream>>>((const uint4*)buf2, c1_bng, c1_bnb, stG,
      nullptr, nullptr, nullptr, nullptr, m[1], invs, (uint4*)buf0, stT);

  // rotation state
  unsigned short *P = buf0, *Q = buf1, *R = buf2;
  const float* stPrev = stT;
  const float* gPrev = bn1_g;
  const float* bPrev = bn1_b;

  for (int i=0;i<3;i++){
    float* stCur = stT + (i+1)*1024;
    k_agg_csr<<<gagg,256,0,stream>>>((const _Float16*)P, off, deg, srcs, ceps+i,
                                  stPrev, gPrev, bPrev, (_Float16*)Q, stG);
    k_gemm6<false><<<gmfma,256,0,stream>>>((const _Float16*)Q, (const _Float16*)wt[1+i],
        cb1 + (size_t)i*HD, (_Float16*)R, nullptr, stCur, NN);
    k_gemm6<true><<<gmfma,256,0,stream>>>((const _Float16*)R, (const _Float16*)wt[4+i],
        cb2 + (size_t)i*HD, (_Float16*)Q, stG, nullptr, NN);
    k_bn_apply_stats<true><<<512,256,0,stream>>>((const uint4*)Q, cbn_g + (size_t)i*HD, cbn_b + (size_t)i*HD, stG,
        (const uint4*)P, stPrev, gPrev, bPrev, m[i+2], invs, (uint4*)R, stCur);
    unsigned short* tmp = P; P = R; R = tmp;
    stPrev = stCur;
    gPrev = bns_g + (size_t)i*HD;
    bPrev = bns_b + (size_t)i*HD;
  }

  // head: fold final BN affine into lin1 weights (also inits mx/mn), then fused head on raw P
  k_headprep<<<HIDN,256,0,stream>>>(w1t, l1_b, stPrev, gPrev, bPrev, w1s, b1p, mx, mn);
  k_head<<<ghead,256,0,stream>>>((const _Float16*)P, (const _Float16*)w1s, b1p, l2_w, l2_b,
                                 m[4], batch, z2, mx, mn, NN);
  k_final<<<gN,TPB,0,stream>>>(z2, batch, mx, mn, out);
}

// Round 12
// 736.297 us; speedup vs baseline: 1.0840x; 1.0840x over previous
//
#include <hip/hip_runtime.h>
#include <hip/hip_fp16.h>

#define NN 50000
#define NE 150000
#define HD 512
#define HIDN 64
#define BN_EPS 1e-5f
#define SLOPE 0.01f
#define NPART 196   // ceil(NN/256)

typedef _Float16 half8 __attribute__((ext_vector_type(8)));
typedef float floatx4 __attribute__((ext_vector_type(4)));

__device__ __forceinline__ float leaky(float v){ return v > 0.f ? v : SLOPE*v; }
__device__ __forceinline__ float h2fu(unsigned short u){ return __half2float(__ushort_as_half(u)); }
__device__ __forceinline__ unsigned short f2hu(float f){ return __half_as_ushort(__float2half(f)); }
__device__ __forceinline__ unsigned packh2(float a, float b){
  return (unsigned)f2hu(a) | ((unsigned)f2hu(b) << 16);
}

// async global->LDS, 16B per lane. LDS dest must be the WAVE-UNIFORM base;
// HW writes each lane at base + lane*16. Global src is per-lane.
__device__ __forceinline__ void gload16(const _Float16* g, _Float16* l){
  __builtin_amdgcn_global_load_lds(
      (const __attribute__((address_space(1))) void*)g,
      (__attribute__((address_space(3))) void*)l, 16, 0, 0);
}

// ---------------- setup: invs (via inline binary-search counts) + mask0 + deg-zero ----------------
__global__ void k_invs_mask0(const int* __restrict__ batch, const float* __restrict__ x,
                             float* __restrict__ invs, int* __restrict__ m0, int* __restrict__ deg){
  int i = blockIdx.x*blockDim.x + threadIdx.x;
  if (i < NN){
    int g = batch[i];
    int lo = 0, hi = NN;
    while (lo < hi){ int mid = (lo+hi)>>1; if (batch[mid] <  g) lo = mid+1; else hi = mid; }
    int start = lo;
    lo = 0; hi = NN;
    while (lo < hi){ int mid = (lo+hi)>>1; if (batch[mid] <= g) lo = mid+1; else hi = mid; }
    invs[i] = rsqrtf((float)(lo - start));
    m0[i] = (fabsf(x[i]) > 0.f) ? 1 : 0;
    deg[i] = 0;
  }
}
__global__ void k_mask_gather(const int* __restrict__ mi, int* __restrict__ mo,
                              const int* __restrict__ off, const int* __restrict__ deg,
                              const int* __restrict__ srcs){
  int i = blockIdx.x*blockDim.x + threadIdx.x;
  if (i < NN){
    int v = mi[i];
    int o = off[i], d = deg[i];
    for (int j = 0; j < d; j++) v |= mi[srcs[o+j]];
    mo[i] = v ? 1 : 0;
  }
}

// ---------------- CSR build (by dst) ----------------
__global__ void k_deg(const int* __restrict__ dst, int* __restrict__ deg){
  int e = blockIdx.x*blockDim.x + threadIdx.x;
  if (e < NE) atomicAdd(&deg[dst[e]], 1);
}
__global__ void k_scan1(const int* __restrict__ deg, int* __restrict__ part){
  __shared__ int s[256];
  int t = threadIdx.x;
  int i = blockIdx.x*256 + t;
  s[t] = (i < NN) ? deg[i] : 0;
  __syncthreads();
  for (int d = 128; d > 0; d >>= 1){
    if (t < d) s[t] += s[t+d];
    __syncthreads();
  }
  if (t == 0) part[blockIdx.x] = s[0];
}
__global__ void k_scan2(int* __restrict__ part){
  __shared__ int s[256];
  int t = threadIdx.x;
  int own = (t < NPART) ? part[t] : 0;
  s[t] = own;
  __syncthreads();
  for (int d = 1; d < 256; d <<= 1){
    int v = (t >= d) ? s[t-d] : 0;
    __syncthreads();
    s[t] += v;
    __syncthreads();
  }
  if (t < NPART) part[t] = s[t] - own;   // exclusive
}
__global__ void k_scan3(const int* __restrict__ deg, const int* __restrict__ part,
                        int* __restrict__ off, int* __restrict__ cur){
  __shared__ int s[256];
  int t = threadIdx.x;
  int i = blockIdx.x*256 + t;
  int own = (i < NN) ? deg[i] : 0;
  s[t] = own;
  __syncthreads();
  for (int d = 1; d < 256; d <<= 1){
    int v = (t >= d) ? s[t-d] : 0;
    __syncthreads();
    s[t] += v;
    __syncthreads();
  }
  if (i < NN){
    int e = s[t] - own + part[blockIdx.x];
    off[i] = e; cur[i] = e;
  }
}
__global__ void k_scatter(const int* __restrict__ src, const int* __restrict__ dst,
                          int* __restrict__ cur, int* __restrict__ srcs){
  int e = blockIdx.x*blockDim.x + threadIdx.x;
  if (e < NE){
    int pos = atomicAdd(&cur[dst[e]], 1);
    srcs[pos] = src[e];
  }
}

// ---------------- weight prep: all 8 transposes in one launch (z-gridded) ----------------
struct W8 { const float* s[8]; unsigned short* d[8]; int N[8]; };
__global__ void k_w2ht8(W8 p){
  int z = blockIdx.z;
  const float* W = p.s[z]; unsigned short* Wt = p.d[z]; int N = p.N[z];
  int kb = blockIdx.x*32, nb = blockIdx.y*32;
  if (nb >= N) return;
  __shared__ float t[32][33];
  int tx = threadIdx.x & 31, ty = threadIdx.x >> 5;   // 32 x 8
  for (int r = 0; r < 32; r += 8)
    t[ty+r][tx] = W[(size_t)(kb+ty+r)*N + nb+tx];
  __syncthreads();
  for (int r = 0; r < 32; r += 8)
    Wt[(size_t)(nb+ty+r)*HD + kb+tx] = f2hu(t[tx][ty+r]);
}

// ---------------- conv1 front: h0 = (1+eps)x + agg ; also zeros stG/stT ----------------
__global__ void k_sagg_csr(const float* __restrict__ x, const int* __restrict__ off,
                           const int* __restrict__ deg, const int* __restrict__ srcs,
                           const float* __restrict__ epsp, float* __restrict__ h0,
                           float* __restrict__ z1, float* __restrict__ z2){
  int i = blockIdx.x*blockDim.x + threadIdx.x;
  if (i < 1024){ z1[i] = 0.f; z2[i] = 0.f; }
  if (i < NN){
    float s = (1.f + epsp[0]) * x[i];
    int o = off[i], d = deg[i];
    for (int j = 0; j < d; j++) s += x[srcs[o + j]];
    h0[i] = s;
  }
}

// ---------------- conv1 piecewise-linear LUT build ----------------
// A[i,k] = relu(h0[i]*w1[k] + b1[k]) is a 1-D function of scalar h0[i], so
// C[i,:] = relu(A[i,:] @ W2 + b2) is piecewise-linear in h0 with breakpoints
// t_k = -b1[k]/w1[k]. Split by sign(w1): prefix over sorted t for w1>0,
// suffix for w1<0; w1==0 constant folded into pos group at -inf.
//   C_pre[i,n] = h0*(Up[rp,n]+Un[rn,n]) + Vp[rp,n]+Vn[rn,n]   (b2 folded into Vp)
// rp = #{thrP < h0}, rn = #{thrN <= h0}.

__global__ void k_rank(const float* __restrict__ w1, const float* __restrict__ b1,
    float* __restrict__ thrP, float* __restrict__ wP, float* __restrict__ bP, int* __restrict__ idxP,
    float* __restrict__ thrN, float* __restrict__ wN, float* __restrict__ bN, int* __restrict__ idxN)
{
  __shared__ float skey[512];
  const int t = threadIdx.x;          // 512 threads; block 0 = pos, block 1 = neg
  const bool neg = (blockIdx.x == 1);
  const float w = w1[t], b = b1[t];
  const float INF = __builtin_inff();
  float key;
  if (!neg) key = (w > 0.f) ? (-b/w) : ((w == 0.f) ? -INF : INF);
  else      key = (w < 0.f) ? (-b/w) : -INF;
  skey[t] = key;
  __syncthreads();
  int r = 0;
  for (int j = 0; j < 512; j++){
    float kj = skey[j];
    r += (kj < key || (kj == key && j < t)) ? 1 : 0;
  }
  if (!neg){
    thrP[r] = key; idxP[r] = t;
    wP[r] = (w > 0.f) ? w : 0.f;
    bP[r] = (w > 0.f) ? b : ((w == 0.f) ? fmaxf(b, 0.f) : 0.f);
  } else {
    thrN[r] = key; idxN[r] = t;
    wN[r] = (w < 0.f) ? w : 0.f;
    bN[r] = (w < 0.f) ? b : 0.f;
  }
}

// grid dim3(32 /*chunk*/, 2 /*0=pos,1=neg*/), 512 threads (one per output col n)
__global__ void k_pref_chunks(const float* __restrict__ W2,
    const int* __restrict__ idxP, const float* __restrict__ wP, const float* __restrict__ bP,
    const int* __restrict__ idxN, const float* __restrict__ wN, const float* __restrict__ bN,
    float* __restrict__ CU, float* __restrict__ CV)   // [2][32][512]
{
  __shared__ float sw[16], sb[16];
  __shared__ int si[16];
  const int n = threadIdx.x;
  const int c = blockIdx.x;
  const bool neg = (blockIdx.y == 1);
  if (n < 16){
    int j = c*16 + n;
    sw[n] = neg ? wN[j] : wP[j];
    sb[n] = neg ? bN[j] : bP[j];
    si[n] = neg ? idxN[j] : idxP[j];
  }
  __syncthreads();
  float aU = 0.f, aV = 0.f;
  #pragma unroll
  for (int k = 0; k < 16; k++){
    float v = W2[(size_t)si[k]*HD + n];
    aU = fmaf(sw[k], v, aU);
    aV = fmaf(sb[k], v, aV);
  }
  size_t o = ((size_t)blockIdx.y*32 + c)*HD + n;
  CU[o] = aU; CV[o] = aV;
}

// grid dim3(32, 2), 512 threads: base from chunk sums, then emit 16 table rows
__global__ void k_pref_write(const float* __restrict__ W2, const float* __restrict__ b2,
    const int* __restrict__ idxP, const float* __restrict__ wP, const float* __restrict__ bP,
    const int* __restrict__ idxN, const float* __restrict__ wN, const float* __restrict__ bN,
    const float* __restrict__ CU, const float* __restrict__ CV,
    float* __restrict__ Up, float* __restrict__ Vp,
    float* __restrict__ Un, float* __restrict__ Vn)
{
  __shared__ float sw[16], sb[16];
  __shared__ int si[16];
  const int n = threadIdx.x;
  const int c = blockIdx.x;
  const bool neg = (blockIdx.y == 1);
  if (n < 16){
    int j = c*16 + n;
    sw[n] = neg ? wN[j] : wP[j];
    sb[n] = neg ? bN[j] : bP[j];
    si[n] = neg ? idxN[j] : idxP[j];
  }
  __syncthreads();
  float aU = 0.f, aV = 0.f;
  if (!neg){
    aV = b2[n];                               // fold b2 into Vp (all rows)
    for (int cc = 0; cc < c; cc++){
      size_t o = (size_t)cc*HD + n;
      aU += CU[o]; aV += CV[o];
    }
    if (c == 0){ Up[n] = 0.f; Vp[n] = aV; }   // row 0: nothing active
    #pragma unroll
    for (int k = 0; k < 16; k++){
      float v = W2[(size_t)si[k]*HD + n];
      aU = fmaf(sw[k], v, aU);
      aV = fmaf(sb[k], v, aV);
      size_t r = (size_t)(c*16 + k + 1);
      Up[r*HD + n] = aU;
      Vp[r*HD + n] = aV;
    }
  } else {
    for (int cc = c+1; cc < 32; cc++){
      size_t o = ((size_t)32 + cc)*HD + n;
      aU += CU[o]; aV += CV[o];
    }
    if (c == 31){ Un[(size_t)512*HD + n] = 0.f; Vn[(size_t)512*HD + n] = 0.f; }  // empty suffix
    #pragma unroll
    for (int k = 15; k >= 0; k--){
      float v = W2[(size_t)si[k]*HD + n];
      aU = fmaf(sw[k], v, aU);
      aV = fmaf(sb[k], v, aV);
      size_t r = (size_t)(c*16 + k);
      Un[r*HD + n] = aU;
      Vn[r*HD + n] = aV;
    }
  }
}

// ---------------- conv1 via LUT ----------------
__global__ __launch_bounds__(256) void k_conv1_lut(const float* __restrict__ h0,
    const float* __restrict__ thrP, const float* __restrict__ thrN,
    const float* __restrict__ Up, const float* __restrict__ Vp,
    const float* __restrict__ Un, const float* __restrict__ Vn,
    _Float16* __restrict__ C, float* __restrict__ st)
{
  __shared__ float ls[2048], lq[2048];
  const int tid = threadIdx.x;
  const int wave = tid >> 6, lane = tid & 63;
  const int c0 = lane << 3;
  float tP[8], tN[8];
  #pragma unroll
  for (int k = 0; k < 8; k++){ tP[k] = thrP[c0+k]; tN[k] = thrN[c0+k]; }
  float s8[8] = {}, q8[8] = {};
  for (int r = blockIdx.x*4 + wave; r < NN; r += gridDim.x*4){
    float h0v = h0[r];
    int cnt = 0;                        // rp in high 16 bits, rn in low 16 (each <= 512)
    #pragma unroll
    for (int k = 0; k < 8; k++){
      cnt += (tP[k] <  h0v) ? 0x10000 : 0;
      cnt += (tN[k] <= h0v) ? 1 : 0;
    }
    #pragma unroll
    for (int off = 1; off < 64; off <<= 1) cnt += __shfl_xor(cnt, off);
    const int rp = cnt >> 16, rn = cnt & 0xFFFF;
    const float4* up = (const float4*)(Up + ((size_t)rp << 9) + c0);
    const float4* vp = (const float4*)(Vp + ((size_t)rp << 9) + c0);
    const float4* un = (const float4*)(Un + ((size_t)rn << 9) + c0);
    const float4* vn = (const float4*)(Vn + ((size_t)rn << 9) + c0);
    float4 ua = up[0], ub = up[1];
    float4 pa = vp[0], pb = vp[1];
    float4 na = un[0], nb = un[1];
    float4 ma = vn[0], mb = vn[1];
    float v[8];
    v[0] = fmaf(h0v, ua.x + na.x, pa.x + ma.x);
    v[1] = fmaf(h0v, ua.y + na.y, pa.y + ma.y);
    v[2] = fmaf(h0v, ua.z + na.z, pa.z + ma.z);
    v[3] = fmaf(h0v, ua.w + na.w, pa.w + ma.w);
    v[4] = fmaf(h0v, ub.x + nb.x, pb.x + mb.x);
    v[5] = fmaf(h0v, ub.y + nb.y, pb.y + mb.y);
    v[6] = fmaf(h0v, ub.z + nb.z, pb.z + mb.z);
    v[7] = fmaf(h0v, ub.w + nb.w, pb.w + mb.w);
    half8 hv;
    #pragma unroll
    for (int k = 0; k < 8; k++){
      float t = v[k] > 0.f ? v[k] : 0.f;
      hv[k] = (_Float16)t;
      s8[k] += t; q8[k] += t*t;
    }
    ((half8*)C)[(size_t)r*64 + lane] = hv;
  }
  #pragma unroll
  for (int k = 0; k < 8; k++){
    ls[wave*512 + c0 + k] = s8[k];
    lq[wave*512 + c0 + k] = q8[k];
  }
  __syncthreads();
  for (int cc = tid; cc < 512; cc += 256){
    float S = ls[cc] + ls[512+cc] + ls[1024+cc] + ls[1536+cc];
    float Q = lq[cc] + lq[512+cc] + lq[1024+cc] + lq[1536+cc];
    unsafeAtomicAdd(&st[cc], S);
    unsafeAtomicAdd(&st[HD+cc], Q);
  }
}

// ---------------- gather+combine v2: 2 rows/wave x 2-edge unroll (MLP) ----------------
__global__ __launch_bounds__(256) void k_agg_csr(const _Float16* __restrict__ T,
                          const int* __restrict__ off,
                          const int* __restrict__ deg, const int* __restrict__ srcs,
                          const float* __restrict__ epsp,
                          const float* __restrict__ st, const float* __restrict__ g,
                          const float* __restrict__ bb, _Float16* __restrict__ G,
                          float* __restrict__ stGz){
  const int tid = threadIdx.x;
  const int wave = tid >> 6, t = tid & 63;
  if (blockIdx.x == 0){
    for (int c = tid; c < 1024; c += 256) stGz[c] = 0.f;
  }
  const int i0 = blockIdx.x*8 + wave*2;
  if (i0 >= NN) return;
  const int i1 = i0 + 1;
  const bool ok1 = (i1 < NN);
  const int i1c = ok1 ? i1 : i0;
  const int c0 = t << 3;
  const float inv_n = 1.f/(float)NN;
  float sc[8], sh[8];
  #pragma unroll
  for (int k = 0; k < 8; k++){
    int c = c0 + k;
    float mu = st[c]*inv_n;
    float var = st[HD+c]*inv_n - mu*mu;
    float s = g[c]*rsqrtf(var+BN_EPS);
    sc[k] = s; sh[k] = bb[c] - mu*s;
  }
  const half8* Tv = (const half8*)T;
  half8 p0 = Tv[(size_t)i0*64 + t];
  half8 p1 = Tv[(size_t)i1c*64 + t];
  const float ep = 1.f + epsp[0];
  const int o0 = off[i0], d0 = deg[i0];
  const int o1 = off[i1c], d1 = deg[i1c];
  float a0[8], a1[8];
  #pragma unroll
  for (int k = 0; k < 8; k++){ a0[k] = (float)p0[k] * ep; a1[k] = (float)p1[k] * ep; }
  const int jm = d0 > d1 ? d0 : d1;
  int j = 0;
  for (; j + 1 < jm; j += 2){
    int s0a = (j     < d0) ? srcs[o0 + j]     : i0;
    int s0b = (j + 1 < d0) ? srcs[o0 + j + 1] : i0;
    int s1a = (j     < d1) ? srcs[o1 + j]     : i1c;
    int s1b = (j + 1 < d1) ? srcs[o1 + j + 1] : i1c;
    half8 q0a = Tv[(size_t)s0a*64 + t];
    half8 q0b = Tv[(size_t)s0b*64 + t];
    half8 q1a = Tv[(size_t)s1a*64 + t];
    half8 q1b = Tv[(size_t)s1b*64 + t];
    if (j < d0){
      #pragma unroll
      for (int k = 0; k < 8; k++) a0[k] += (float)q0a[k];
      if (j + 1 < d0){
        #pragma unroll
        for (int k = 0; k < 8; k++) a0[k] += (float)q0b[k];
      }
    }
    if (j < d1){
      #pragma unroll
      for (int k = 0; k < 8; k++) a1[k] += (float)q1a[k];
      if (j + 1 < d1){
        #pragma unroll
        for (int k = 0; k < 8; k++) a1[k] += (float)q1b[k];
      }
    }
  }
  if (j < jm){
    int s0a = (j < d0) ? srcs[o0 + j] : i0;
    int s1a = (j < d1) ? srcs[o1 + j] : i1c;
    half8 q0a = Tv[(size_t)s0a*64 + t];
    half8 q1a = Tv[(size_t)s1a*64 + t];
    if (j < d0){
      #pragma unroll
      for (int k = 0; k < 8; k++) a0[k] += (float)q0a[k];
    }
    if (j < d1){
      #pragma unroll
      for (int k = 0; k < 8; k++) a1[k] += (float)q1a[k];
    }
  }
  {
    float cnt0 = ep + (float)d0;
    half8 r0;
    #pragma unroll
    for (int k = 0; k < 8; k++) r0[k] = (_Float16)fmaf(sc[k], a0[k], cnt0*sh[k]);
    ((half8*)G)[(size_t)i0*64 + t] = r0;
  }
  if (ok1){
    float cnt1 = ep + (float)d1;
    half8 r1;
    #pragma unroll
    for (int k = 0; k < 8; k++) r1[k] = (_Float16)fmaf(sc[k], a1[k], cnt1*sh[k]);
    ((half8*)G)[(size_t)i1*64 + t] = r1;
  }
}

// ---------------- MFMA GEMM v5: counted-vmcnt pipeline, BK=32, 2 LDS buffers, 4 blocks/CU ----
// r8/r10: 50.5-51.4us, VGPR 64, occupancy 29%. Flat 1568-grid (r11's persistent 2-tile
// variant regressed to 88us via lost A-panel L2 locality -> reverted). Final form.
template<bool STATS>
__global__ __launch_bounds__(256, 4) void k_gemm5(const _Float16* __restrict__ A,
    const _Float16* __restrict__ Wt, const float* __restrict__ bias,
    _Float16* __restrict__ C, float* __restrict__ st, float* __restrict__ zbuf, int M)
{
  constexpr int BK = 32;
  constexpr int TS = 128*BK;                 // 4096 halves = 8KB per matrix per buffer
  __shared__ __attribute__((aligned(16))) _Float16 pool[4*TS];   // 2 x (A,B) = 32KB
  const int tid = threadIdx.x;
  if (zbuf && blockIdx.x == 0){
    for (int c = tid; c < 1024; c += 256) zbuf[c] = 0.f;
  }
  const int Mb = (M + 127) >> 7;
  const int F = blockIdx.x;
  const int S = F & 7, rr = F >> 3;
  const int bx = rr & 3, q = rr >> 2;
  const int by = q*8 + S;
  if (by >= Mb) return;
  const int m0 = by * 128, n0 = bx * 128;
  const int w = tid >> 6, lane = tid & 63;
  const int wm = (w >> 1) << 6, wn = (w & 1) << 6;
  const int quad = lane >> 4, l16 = lane & 15;

  floatx4 acc[4][4] = {};

  // staging: tile = 128 rows x 32 halves = 512 chunks of 16B; thread covers {tid, 256+tid}.
  const _Float16 *ga[2], *gb[2];
  #pragma unroll
  for (int j = 0; j < 2; j++){
    int c = j*256 + tid;
    int row = c >> 2, kc = (c & 3) << 3;
    int rA = m0 + row; if (rA > M-1) rA = M-1;
    ga[j] = A  + (size_t)rA*HD + kc;
    gb[j] = Wt + (size_t)(n0 + row)*HD + kc;
  }

  auto stage = [&](int kt, int buf){
    _Float16* As = pool + buf*2*TS;
    _Float16* Bs = As + TS;
    #pragma unroll
    for (int j = 0; j < 2; j++){
      const int lb = (j*256 + w*64)*8;       // wave-uniform dest base (chunks) * 8 halves
      gload16(ga[j] + kt*BK, As + lb);
      gload16(gb[j] + kt*BK, Bs + lb);
    }
  };

  stage(0, 0);                               // 4 vmem/thread in flight
  stage(1, 1);                               // 8 in flight
  #pragma unroll
  for (int kt = 0; kt < 16; kt++){
    __builtin_amdgcn_sched_barrier(0);       // pin iteration boundary (vmcnt bookkeeping)
    if (kt == 15) asm volatile("s_waitcnt vmcnt(0)" ::: "memory");
    else          asm volatile("s_waitcnt vmcnt(4)" ::: "memory");  // tile kt landed; kt+1 in flight
    __builtin_amdgcn_s_barrier();            // everyone's tile-kt portion landed
    __builtin_amdgcn_sched_barrier(0);
    const _Float16* As = pool + (kt & 1)*2*TS;
    const _Float16* Bs = As + TS;
    half8 af[4], bf[4];
    #pragma unroll
    for (int t4 = 0; t4 < 4; t4++){
      af[t4] = *(const half8*)(As + (wm + t4*16 + l16)*BK + quad*8);
      bf[t4] = *(const half8*)(Bs + (wn + t4*16 + l16)*BK + quad*8);
    }
    #pragma unroll
    for (int mi = 0; mi < 4; mi++){
      #pragma unroll
      for (int ni = 0; ni < 4; ni++){
        acc[mi][ni] = __builtin_amdgcn_mfma_f32_16x16x32_f16(af[mi], bf[ni], acc[mi][ni], 0, 0, 0);
      }
    }
    __builtin_amdgcn_sched_barrier(0);       // ds_reads stay before the WAR barrier
    __builtin_amdgcn_s_barrier();            // all waves done reading buf (kt&1)
    __builtin_amdgcn_sched_barrier(0);
    if (kt < 14) stage(kt+2, kt & 1);        // overwrite now-safe buffer; stays in flight
  }
  __syncthreads();                           // full drain before pool reuse

  // epilogue: bias+relu (+stats); D bounced through pool in two 64-row passes (CP=136)
  constexpr int CP = 136;
  _Float16* Ds = pool;                       // 64*136 = 8704 halves <= 16384 pool
  float bs4[4];
  #pragma unroll
  for (int ni = 0; ni < 4; ni++) bs4[ni] = bias[n0 + wn + ni*16 + l16];
  float sv[4] = {0,0,0,0}, qv[4] = {0,0,0,0};
  #pragma unroll
  for (int half = 0; half < 2; half++){
    const int hb = half << 6;                // 0 or 64
    if (wm == hb){
      #pragma unroll
      for (int ni = 0; ni < 4; ni++){
        int ccol = wn + ni*16 + l16;
        #pragma unroll
        for (int mi = 0; mi < 4; mi++){
          #pragma unroll
          for (int reg = 0; reg < 4; reg++){
            int row_l = wm + mi*16 + quad*4 + reg;
            float v = acc[mi][ni][reg] + bs4[ni];
            v = v > 0.f ? v : 0.f;
            Ds[(row_l - hb)*CP + ccol] = (_Float16)v;
            if (STATS && (m0 + row_l < M)){ sv[ni] += v; qv[ni] += v*v; }
          }
        }
      }
    }
    __syncthreads();
    #pragma unroll
    for (int s = 0; s < 4; s++){
      int chunk = tid + s*256;        // 0..1023: 64 rows x 16 col-chunks
      int row_l = chunk >> 4;
      int colc  = (chunk & 15) << 3;
      int r = m0 + hb + row_l;
      if (r < M)
        *(half8*)&C[(size_t)r*HD + n0 + colc] = *(const half8*)&Ds[row_l*CP + colc];
    }
    __syncthreads();
  }
  if (STATS){
    #pragma unroll
    for (int ni = 0; ni < 4; ni++){
      float s = sv[ni], qq = qv[ni];
      s += __shfl_xor(s, 16); s += __shfl_xor(s, 32);
      qq += __shfl_xor(qq, 16); qq += __shfl_xor(qq, 32);
      if (quad == 0){
        int ccol = n0 + wn + ni*16 + l16;
        unsafeAtomicAdd(&st[ccol], s);
        unsafeAtomicAdd(&st[HD+ccol], qq);
      }
    }
  }
}

// ---------------- head prep: fold last BN affine into lin1 weights; init mx/mn ----------------
__global__ void k_headprep(const unsigned short* __restrict__ w1t, const float* __restrict__ b1,
    const float* __restrict__ st, const float* __restrict__ g, const float* __restrict__ bb,
    unsigned short* __restrict__ w1s, float* __restrict__ b1p,
    unsigned* __restrict__ mx, unsigned* __restrict__ mn){
  int n = blockIdx.x; int t = threadIdx.x;
  if (n == 0 && t < 64){ mx[t] = 0u; }
  if (n == 1 && t < 64){ mn[t] = 0xFFFFFFFFu; }
  __shared__ float red[256];
  const float inv_n = 1.f/(float)NN;
  float acc = 0.f;
  #pragma unroll
  for (int kk = 0; kk < 2; kk++){
    int k = t + kk*256;
    float mu = st[k]*inv_n;
    float var = st[HD+k]*inv_n - mu*mu;
    float sc = g[k]*rsqrtf(var+BN_EPS);
    float sh = bb[k] - mu*sc;
    float wv = h2fu(w1t[(size_t)n*HD + k]);
    w1s[(size_t)n*HD + k] = f2hu(sc*wv);
    acc += sh*wv;
  }
  red[t] = acc; __syncthreads();
  for (int d = 128; d > 0; d >>= 1){ if (t < d) red[t] += red[t+d]; __syncthreads(); }
  if (t == 0) b1p[n] = b1[n] + red[0];
}

// ---------------- fused head (pipelined) with per-block LDS min/max reduction ----------------
__global__ __launch_bounds__(256) void k_head(const _Float16* __restrict__ Xh,
    const _Float16* __restrict__ W1t, const float* __restrict__ b1,
    const float* __restrict__ w2, const float* __restrict__ b2p,
    const int* __restrict__ mask, const int* __restrict__ batch,
    float* __restrict__ z2, unsigned* __restrict__ mx, unsigned* __restrict__ mn, int M)
{
  constexpr int PK = 72;
  __shared__ __attribute__((aligned(16))) _Float16 As[128*PK];
  __shared__ __attribute__((aligned(16))) _Float16 Bs[64*PK];
  __shared__ unsigned smx[64], smn[64];
  const int tid = threadIdx.x;
  const int m0 = blockIdx.x * 128;
  const int w = tid >> 6, lane = tid & 63;
  const int wm = w << 5;
  const int quad = lane >> 4, l16 = lane & 15;

  if (tid < 64){ smx[tid] = 0u; smn[tid] = 0xFFFFFFFFu; }

  floatx4 acc[2][4] = {};

  const int srow = tid >> 1;
  const int skoff = (tid & 1) << 5;
  int arow = m0 + srow; if (arow > M-1) arow = M-1;
  const _Float16* Ag = Xh + (size_t)arow*HD + skoff;
  _Float16* Asw = As + srow*PK + skoff;
  const int brow = tid >> 2;
  const int bkoff = (tid & 3) << 4;
  const _Float16* Bg = W1t + (size_t)brow*HD + bkoff;
  _Float16* Bsw = Bs + brow*PK + bkoff;

  half8 ca[4], cb[2], na[4], nb[2];
  #pragma unroll
  for (int j = 0; j < 4; j++) ca[j] = *(const half8*)(Ag + j*8);
  cb[0] = *(const half8*)(Bg); cb[1] = *(const half8*)(Bg + 8);

  #pragma unroll
  for (int kt = 0; kt < HD; kt += 64){
    __syncthreads();
    #pragma unroll
    for (int j = 0; j < 4; j++) *(half8*)(Asw + j*8) = ca[j];
    *(half8*)(Bsw) = cb[0]; *(half8*)(Bsw + 8) = cb[1];
    if (kt + 64 < HD){
      #pragma unroll
      for (int j = 0; j < 4; j++) na[j] = *(const half8*)(Ag + kt + 64 + j*8);
      nb[0] = *(const half8*)(Bg + kt + 64); nb[1] = *(const half8*)(Bg + kt + 72);
    }
    __syncthreads();
    #pragma unroll
    for (int k0 = 0; k0 < 64; k0 += 32){
      half8 af[2], bf[4];
      #pragma unroll
      for (int mi = 0; mi < 2; mi++) af[mi] = *(const half8*)&As[(wm + mi*16 + l16)*PK + k0 + quad*8];
      #pragma unroll
      for (int ni = 0; ni < 4; ni++) bf[ni] = *(const half8*)&Bs[(ni*16 + l16)*PK + k0 + quad*8];
      #pragma unroll
      for (int mi = 0; mi < 2; mi++){
        #pragma unroll
        for (int ni = 0; ni < 4; ni++){
          acc[mi][ni] = __builtin_amdgcn_mfma_f32_16x16x32_f16(af[mi], bf[ni], acc[mi][ni], 0, 0, 0);
        }
      }
    }
    #pragma unroll
    for (int j = 0; j < 4; j++) ca[j] = na[j];
    cb[0] = nb[0]; cb[1] = nb[1];
  }

  float b1v[4], w2v[4];
  #pragma unroll
  for (int ni = 0; ni < 4; ni++){ b1v[ni] = b1[ni*16 + l16]; w2v[ni] = w2[ni*16 + l16]; }
  const float b2 = b2p[0];
  #pragma unroll
  for (int mi = 0; mi < 2; mi++){
    #pragma unroll
    for (int reg = 0; reg < 4; reg++){
      int r = m0 + wm + mi*16 + quad*4 + reg;
      bool ok = r < M;
      float mk = (ok && mask[r]) ? 1.f : 0.f;
      float t = 0.f;
      #pragma unroll
      for (int ni = 0; ni < 4; ni++){
        float v = leaky(acc[mi][ni][reg] + b1v[ni]) * mk;
        t += v * w2v[ni];
      }
      t += __shfl_xor(t, 1); t += __shfl_xor(t, 2);
      t += __shfl_xor(t, 4); t += __shfl_xor(t, 8);
      if (l16 == 0 && ok){
        float zv = leaky(t + b2) * mk;
        z2[r] = zv;
        unsigned u = __float_as_uint(zv);
        unsigned key = (u & 0x80000000u) ? ~u : (u | 0x80000000u);
        int gg = batch[r];
        atomicMax(&smx[gg], key); atomicMin(&smn[gg], key);
      }
    }
  }
  __syncthreads();
  if (tid < 64){
    unsigned vx = smx[tid], vn = smn[tid];
    if (vx != 0u)          atomicMax(&mx[tid], vx);
    if (vn != 0xFFFFFFFFu) atomicMin(&mn[tid], vn);
  }
}

// ---------------- BN apply v3: 4 rows/wave for MLP ----------------
template<bool RESID>
__global__ __launch_bounds__(256) void k_bn_apply_stats(const uint4* __restrict__ Hu,
    const float* __restrict__ g, const float* __restrict__ bb, const float* __restrict__ st,
    const uint4* __restrict__ Pu, const float* __restrict__ stP,
    const float* __restrict__ gP, const float* __restrict__ bP,
    const int* __restrict__ mask, const float* __restrict__ invs,
    uint4* __restrict__ Tu, float* __restrict__ st2)
{
  __shared__ float ls[2048], lq[2048];
  const int tid = threadIdx.x;
  const int wave = tid >> 6, lane = tid & 63;
  const int c8 = lane << 3;
  const float inv_n = 1.f/(float)NN;
  float sc[8], sh[8], pc[8], ps[8];
  #pragma unroll
  for (int k = 0; k < 8; k++){
    int c = c8 + k;
    float mu = st[c]*inv_n;
    float var = st[HD+c]*inv_n - mu*mu;
    float s = g[c]*rsqrtf(var+BN_EPS);
    sc[k] = s; sh[k] = bb[c] - mu*s;
    if (RESID){
      float muP = stP[c]*inv_n;
      float varP = stP[HD+c]*inv_n - muP*muP;
      float sP = gP[c]*rsqrtf(varP+BN_EPS);
      pc[k] = sP; ps[k] = bP[c] - muP*sP;
    }
  }
  float s8[8] = {}, q8[8] = {};

  auto proc = [&](uint4 u, uint4 p, float ww, int r, bool ok){
    if (!ok) return;
    float hv[8];
    hv[0]=h2fu(u.x&0xFFFF); hv[1]=h2fu(u.x>>16);
    hv[2]=h2fu(u.y&0xFFFF); hv[3]=h2fu(u.y>>16);
    hv[4]=h2fu(u.z&0xFFFF); hv[5]=h2fu(u.z>>16);
    hv[6]=h2fu(u.w&0xFFFF); hv[7]=h2fu(u.w>>16);
    float v[8];
    #pragma unroll
    for (int k = 0; k < 8; k++) v[k] = leaky(fmaf(hv[k], sc[k], sh[k]));
    if (RESID){
      float pv[8];
      pv[0]=h2fu(p.x&0xFFFF); pv[1]=h2fu(p.x>>16);
      pv[2]=h2fu(p.y&0xFFFF); pv[3]=h2fu(p.y>>16);
      pv[4]=h2fu(p.z&0xFFFF); pv[5]=h2fu(p.z>>16);
      pv[6]=h2fu(p.w&0xFFFF); pv[7]=h2fu(p.w>>16);
      #pragma unroll
      for (int k = 0; k < 8; k++) v[k] += fmaf(pv[k], pc[k], ps[k]);
    }
    uint4 o;
    o.x = packh2(v[0]*ww, v[1]*ww); o.y = packh2(v[2]*ww, v[3]*ww);
    o.z = packh2(v[4]*ww, v[5]*ww); o.w = packh2(v[6]*ww, v[7]*ww);
    Tu[(size_t)r*64 + lane] = o;
    #pragma unroll
    for (int k = 0; k < 8; k++){ float t = v[k]*ww; s8[k] += t; q8[k] += t*t; }
  };

  for (int r0 = blockIdx.x*16 + wave*4; r0 < NN; r0 += gridDim.x*16){
    const int r1 = r0 + 1, r2 = r0 + 2, r3 = r0 + 3;
    const bool ok1 = r1 < NN, ok2 = r2 < NN, ok3 = r3 < NN;
    const int r1c = ok1 ? r1 : r0, r2c = ok2 ? r2 : r0, r3c = ok3 ? r3 : r0;
    uint4 u0 = Hu[(size_t)r0*64 + lane];
    uint4 u1 = Hu[(size_t)r1c*64 + lane];
    uint4 u2 = Hu[(size_t)r2c*64 + lane];
    uint4 u3 = Hu[(size_t)r3c*64 + lane];
    uint4 p0{}, p1{}, p2{}, p3{};
    if (RESID){
      p0 = Pu[(size_t)r0*64 + lane];
      p1 = Pu[(size_t)r1c*64 + lane];
      p2 = Pu[(size_t)r2c*64 + lane];
      p3 = Pu[(size_t)r3c*64 + lane];
    }
    float ww0 = mask[r0]  ? invs[r0]  : 0.f;
    float ww1 = mask[r1c] ? invs[r1c] : 0.f;
    float ww2 = mask[r2c] ? invs[r2c] : 0.f;
    float ww3 = mask[r3c] ? invs[r3c] : 0.f;
    proc(u0, p0, ww0, r0, true);
    proc(u1, p1, ww1, r1, ok1);
    proc(u2, p2, ww2, r2, ok2);
    proc(u3, p3, ww3, r3, ok3);
  }
  #pragma unroll
  for (int k = 0; k < 8; k++){
    ls[wave*512 + c8 + k] = s8[k];
    lq[wave*512 + c8 + k] = q8[k];
  }
  __syncthreads();
  for (int cc = tid; cc < 512; cc += 256){
    float S = ls[cc] + ls[512+cc] + ls[1024+cc] + ls[1536+cc];
    float Q = lq[cc] + lq[512+cc] + lq[1024+cc] + lq[1536+cc];
    unsafeAtomicAdd(&st2[cc], S);
    unsafeAtomicAdd(&st2[HD+cc], Q);
  }
}

// ---------------- final normalize ----------------
__device__ __forceinline__ float funkey(unsigned k){
  unsigned u = (k & 0x80000000u) ? (k & 0x7fffffffu) : ~k;
  return __uint_as_float(u);
}
__global__ void k_final(const float* __restrict__ z2, const int* __restrict__ batch,
                        const unsigned* __restrict__ mx, const unsigned* __restrict__ mn,
                        float* __restrict__ out){
  int i = blockIdx.x*blockDim.x + threadIdx.x;
  if (i < NN){
    int g = batch[i];
    float bmax = funkey(mx[g]), bmin = funkey(mn[g]);
    out[i] = (z2[i] - bmin) / ((bmax + 1e-6f) - bmin);
  }
}

extern "C" void kernel_launch(void* const* d_in, const int* in_sizes, int n_in,
                              void* d_out, int out_size, void* d_ws, size_t ws_size,
                              hipStream_t stream)
{
  const float* x      = (const float*)d_in[0];
  const int*   ei     = (const int*)d_in[1];
  const int*   src    = ei;
  const int*   dst    = ei + NE;
  const int*   batch  = (const int*)d_in[2];
  const float* c1_w1  = (const float*)d_in[3];
  const float* c1_b1  = (const float*)d_in[4];
  const float* c1_w2  = (const float*)d_in[5];
  const float* c1_b2  = (const float*)d_in[6];
  const float* c1_bng = (const float*)d_in[7];
  const float* c1_bnb = (const float*)d_in[8];
  const float* eps1   = (const float*)d_in[9];
  const float* bn1_g  = (const float*)d_in[10];
  const float* bn1_b  = (const float*)d_in[11];
  const float* cw1    = (const float*)d_in[12];
  const float* cb1    = (const float*)d_in[13];
  const float* cw2    = (const float*)d_in[14];
  const float* cb2    = (const float*)d_in[15];
  const float* cbn_g  = (const float*)d_in[16];
  const float* cbn_b  = (const float*)d_in[17];
  const float* ceps   = (const float*)d_in[18];
  const float* bns_g  = (const float*)d_in[19];
  const float* bns_b  = (const float*)d_in[20];
  const float* l1_w   = (const float*)d_in[21];
  const float* l1_b   = (const float*)d_in[22];
  const float* l2_w   = (const float*)d_in[23];
  const float* l2_b   = (const float*)d_in[24];
  float* out = (float*)d_out;

  const size_t NH = (size_t)NN*HD;
  unsigned short* buf0 = (unsigned short*)d_ws;   // fp16 NH
  unsigned short* buf1 = buf0 + NH;               // fp16 NH
  unsigned short* buf2 = buf1 + NH;               // fp16 NH
  float* h0   = (float*)(buf2 + NH);              // NN
  float* invs = h0 + NN;                          // NN
  float* z2   = invs + NN;                        // NN
  float* stG  = z2 + NN;                          // 1024
  float* stT  = stG + 1024;                       // 4 x 1024
  unsigned* mx = (unsigned*)(stT + 4*1024);       // 64
  unsigned* mn = mx + 64;                         // 64
  float* b1p  = (float*)(mn + 64);                // 64
  int* part = (int*)(b1p + 64);                   // 256 (scan partials)
  int* deg  = part + 256;                         // NN
  int* off  = deg + NN;                           // NN
  int* cur  = off + NN;                           // NN
  int* srcs = cur + NN;                           // NE
  int* m[5];
  m[0] = srcs + NE;
  for (int k=1;k<5;k++) m[k] = m[k-1] + NN;
  unsigned short* wt[7];
  wt[0] = (unsigned short*)(m[4] + NN);
  for (int k=1;k<7;k++) wt[k] = wt[k-1] + HD*HD;
  unsigned short* w1t = wt[6] + HD*HD;            // 64*512 fp16
  unsigned short* w1s = w1t + (size_t)HIDN*HD;    // 64*512 fp16 (affine-folded)

  // conv1 LUT tables live in buf1 (dead until first k_agg_csr writes Q=buf1)
  float* tab  = (float*)buf1;
  float* thrP = tab;                              // 512
  float* wPs  = thrP + 512;
  float* bPs  = wPs + 512;
  float* thrN = bPs + 512;
  float* wNs  = thrN + 512;
  float* bNs  = wNs + 512;
  int*   idxP = (int*)(bNs + 512);                // 512
  int*   idxN = idxP + 512;                       // 512
  float* Up   = (float*)(idxN + 512);             // 513*512
  float* Vp   = Up + 513*512;
  float* Un   = Vp + 513*512;
  float* Vn   = Un + 513*512;
  float* CU   = Vn + 513*512;                     // [2][32][512] chunk sums
  float* CV   = CU + 2*32*512;                    // total ~4.5 MB << 51.2 MB

  const int TPB = 256;
  dim3 gN((NN+TPB-1)/TPB);
  dim3 gE((NE+TPB-1)/TPB);
  const int Mb = (NN+127)/128;          // 391
  const int QB = (Mb+7)/8;              // 49
  dim3 gmfma(8*4*QB);                   // 1568 swizzled 1D blocks
  dim3 ghead((NN+127)/128);
  dim3 gagg((NN+7)/8);                  // 2 rows/wave

  // setup
  k_invs_mask0<<<gN, TPB, 0, stream>>>(batch, x, invs, m[0], deg);
  // CSR by dst (parallel 3-phase scan)
  k_deg<<<gE,TPB,0,stream>>>(dst, deg);
  k_scan1<<<NPART,256,0,stream>>>(deg, part);
  k_scan2<<<1,256,0,stream>>>(part);
  k_scan3<<<NPART,256,0,stream>>>(deg, part, off, cur);
  k_scatter<<<gE,TPB,0,stream>>>(src, dst, cur, srcs);
  // masks via CSR gather
  for (int k=1;k<5;k++)
    k_mask_gather<<<gN,TPB,0,stream>>>(m[k-1], m[k], off, deg, srcs);
  // weight prep: all 8 transposes in one launch
  W8 wp;
  wp.s[0] = c1_w2; wp.d[0] = wt[0]; wp.N[0] = HD;
  for (int i=0;i<3;i++){
    wp.s[1+i] = cw1 + (size_t)i*HD*HD; wp.d[1+i] = wt[1+i]; wp.N[1+i] = HD;
    wp.s[4+i] = cw2 + (size_t)i*HD*HD; wp.d[4+i] = wt[4+i]; wp.N[4+i] = HD;
  }
  wp.s[7] = l1_w; wp.d[7] = w1t; wp.N[7] = HIDN;
  k_w2ht8<<<dim3(HD/32, HD/32, 8),256,0,stream>>>(wp);

  // conv1 LUT build: parallel rank-sort + chunked prefix/suffix tables
  k_rank<<<2,512,0,stream>>>(c1_w1, c1_b1, thrP, wPs, bPs, idxP, thrN, wNs, bNs, idxN);
  k_pref_chunks<<<dim3(32,2),512,0,stream>>>(c1_w2, idxP, wPs, bPs, idxN, wNs, bNs, CU, CV);
  k_pref_write<<<dim3(32,2),512,0,stream>>>(c1_w2, c1_b2, idxP, wPs, bPs, idxN, wNs, bNs,
                                            CU, CV, Up, Vp, Un, Vn);

  // conv1: h0 (zeros stG,stT[0]), LUT lookup(+stats)->buf2, apply<false>->buf0
  k_sagg_csr<<<gN,TPB,0,stream>>>(x, off, deg, srcs, eps1, h0, stG, stT);
  k_conv1_lut<<<512,256,0,stream>>>(h0, thrP, thrN, Up, Vp, Un, Vn, (_Float16*)buf2, stG);
  k_bn_apply_stats<false><<<512,256,0,stream>>>((const uint4*)buf2, c1_bng, c1_bnb, stG,
      nullptr, nullptr, nullptr, nullptr, m[1], invs, (uint4*)buf0, stT);

  // rotation state
  unsigned short *P = buf0, *Q = buf1, *R = buf2;
  const float* stPrev = stT;
  const float* gPrev = bn1_g;
  const float* bPrev = bn1_b;

  for (int i=0;i<3;i++){
    float* stCur = stT + (i+1)*1024;
    k_agg_csr<<<gagg,256,0,stream>>>((const _Float16*)P, off, deg, srcs, ceps+i,
                                  stPrev, gPrev, bPrev, (_Float16*)Q, stG);
    k_gemm5<false><<<gmfma,256,0,stream>>>((const _Float16*)Q, (const _Float16*)wt[1+i],
        cb1 + (size_t)i*HD, (_Float16*)R, nullptr, stCur, NN);
    k_gemm5<true><<<gmfma,256,0,stream>>>((const _Float16*)R, (const _Float16*)wt[4+i],
        cb2 + (size_t)i*HD, (_Float16*)Q, stG, nullptr, NN);
    k_bn_apply_stats<true><<<512,256,0,stream>>>((const uint4*)Q, cbn_g + (size_t)i*HD, cbn_b + (size_t)i*HD, stG,
        (const uint4*)P, stPrev, gPrev, bPrev, m[i+2], invs, (uint4*)R, stCur);
    unsigned short* tmp = P; P = R; R = tmp;
    stPrev = stCur;
    gPrev = bns_g + (size_t)i*HD;
    bPrev = bns_b + (size_t)i*HD;
  }

  // head: fold final BN affine into lin1 weights (also inits mx/mn), then fused head on raw P
  k_headprep<<<HIDN,256,0,stream>>>(w1t, l1_b, stPrev, gPrev, bPrev, w1s, b1p, mx, mn);
  k_head<<<ghead,256,0,stream>>>((const _Float16*)P, (const _Float16*)w1s, b1p, l2_w, l2_b,
                                 m[4], batch, z2, mx, mn, NN);
  k_final<<<gN,TPB,0,stream>>>(z2, batch, mx, mn, out);
}